// Round 2
// baseline (322.613 us; speedup 1.0000x reference)
//
#include <hip/hip_runtime.h>
#include <hip/hip_bf16.h>

// Problem constants (from reference): inputs (8, 64, 16, 32, 32) fp32, embedding (1024, 64) fp32
#define BDIM   8
#define CDIM   64
#define TDIM   16
#define HDIM   32
#define WDIM   32
#define THW    16384            // T*H*W
#define NTOT   131072           // B*T*H*W flat vectors
#define KDIM   1024
#define QOFF   0
#define QELEMS 8388608          // B*C*T*H*W = 8*64*16*32*32
#define LOSS_OFF 8388608
#define IDX_OFF  8388610
#define BN     64               // n-tile per block
#define BK     64               // k-chunk

// ---- prep: zero loss accumulators (d_out is poisoned 0xAA), compute ||e||^2 ----
__global__ void vq_prep(const float* __restrict__ emb, float* __restrict__ e2,
                        float* __restrict__ out) {
    int k = blockIdx.x * 256 + threadIdx.x;   // grid = 4*256 = 1024
    if (k == 0) { out[LOSS_OFF] = 0.0f; out[LOSS_OFF + 1] = 0.0f; }
    const float4* row = (const float4*)(emb + (size_t)k * CDIM);
    float s = 0.0f;
    #pragma unroll
    for (int i = 0; i < 16; ++i) {
        float4 v = row[i];
        s += v.x * v.x + v.y * v.y + v.z * v.z + v.w * v.w;
    }
    e2[k] = s;
}

// ---- main: distances + argmin + gather/transpose write + loss partials ----
__global__ __launch_bounds__(256) void vq_main(const float* __restrict__ in,
                                               const float* __restrict__ emb,
                                               const float* __restrict__ e2,
                                               float* __restrict__ out) {
    __shared__ float Xs[CDIM][BN + 4];   // [c][n]  stride 68: float4-aligned, <=2-way bank alias
    __shared__ float Es[CDIM][BK + 4];   // [c][k]
    __shared__ float redv[BN][17];
    __shared__ int   redi[BN][17];
    __shared__ int   idxs[BN];
    __shared__ float wsum[4];

    const int tid  = threadIdx.x;
    const int n0   = blockIdx.x * BN;          // global flat-n base (64 | THW so single b)
    const int b    = n0 >> 14;                 // n0 / THW
    const int thw0 = n0 & (THW - 1);
    const float* inb = in + (size_t)b * CDIM * THW + thw0;

    // stage X tile: coalesced (64 consecutive n per c)
    {
        const int nl = tid & 63;
        const int cb = tid >> 6;               // 0..3
        #pragma unroll
        for (int r = 0; r < 16; ++r) {
            const int c = r * 4 + cb;
            Xs[c][nl] = inb[(size_t)c * THW + nl];
        }
    }

    const int i = tid & 15;                    // n-group: n_local = 4i..4i+3
    const int j = tid >> 4;                    // k-group: k_local = 4j..4j+3

    float bestv[4];
    int   besti[4];
    #pragma unroll
    for (int q = 0; q < 4; ++q) { bestv[q] = 3.4e38f; besti[q] = 0; }

    for (int k0 = 0; k0 < KDIM; k0 += BK) {
        // stage E chunk transposed: read coalesced rows, write [c][k]
        {
            const int cc = tid & 63;
            const int kb = tid >> 6;
            #pragma unroll
            for (int r = 0; r < 16; ++r) {
                const int kl = r * 4 + kb;
                Es[cc][kl] = emb[(size_t)(k0 + kl) * CDIM + cc];
            }
        }
        __syncthreads();

        float acc[4][4] = {{0.f,0.f,0.f,0.f},{0.f,0.f,0.f,0.f},
                           {0.f,0.f,0.f,0.f},{0.f,0.f,0.f,0.f}};
        #pragma unroll 8
        for (int c = 0; c < CDIM; ++c) {
            const float4 xv = *(const float4*)(&Xs[c][4 * i]);
            const float4 ev = *(const float4*)(&Es[c][4 * j]);
            const float xa[4] = {xv.x, xv.y, xv.z, xv.w};
            const float ea[4] = {ev.x, ev.y, ev.z, ev.w};
            #pragma unroll
            for (int q = 0; q < 4; ++q)
                #pragma unroll
                for (int kk = 0; kk < 4; ++kk)
                    acc[q][kk] = fmaf(xa[q], ea[kk], acc[q][kk]);
        }

        // fold distances d = ||e||^2 - 2 x.e  (||x||^2 constant per n, irrelevant to argmin)
        #pragma unroll
        for (int kk = 0; kk < 4; ++kk) {
            const int kg = k0 + 4 * j + kk;
            const float ek2 = e2[kg];
            #pragma unroll
            for (int q = 0; q < 4; ++q) {
                const float d = fmaf(-2.0f, acc[q][kk], ek2);
                if (d < bestv[q]) { bestv[q] = d; besti[q] = kg; }  // strict < keeps lowest k
            }
        }
        __syncthreads();
    }

    // reduce argmin across the 16 j-threads per n
    #pragma unroll
    for (int q = 0; q < 4; ++q) { redv[4 * i + q][j] = bestv[q]; redi[4 * i + q][j] = besti[q]; }
    __syncthreads();
    if (tid < BN) {
        float bv = redv[tid][0]; int bi = redi[tid][0];
        #pragma unroll
        for (int jj = 1; jj < 16; ++jj) {
            const float v = redv[tid][jj]; const int ii = redi[tid][jj];
            if (v < bv || (v == bv && ii < bi)) { bv = v; bi = ii; }
        }
        idxs[tid] = bi;
        out[IDX_OFF + n0 + tid] = (float)bi;   // indices as float values
    }
    __syncthreads();

    // gather embedding rows, write quantized transposed (coalesced), accumulate MSE partial
    float lsum = 0.0f;
    {
        const int nl = tid & 63;
        const int cb = tid >> 6;
        const int idx = idxs[nl];
        const float* er = emb + (size_t)idx * CDIM;
        float* outb = out + QOFF + (size_t)b * CDIM * THW + thw0;
        #pragma unroll
        for (int r = 0; r < 16; ++r) {
            const int c = r * 4 + cb;
            const float qv = er[c];
            const float xv = Xs[c][nl];
            outb[(size_t)c * THW + nl] = qv;
            const float d = qv - xv;
            lsum = fmaf(d, d, lsum);
        }
    }
    // wave + block reduction of loss partial
    #pragma unroll
    for (int off = 32; off > 0; off >>= 1) lsum += __shfl_down(lsum, off, 64);
    if ((tid & 63) == 0) wsum[tid >> 6] = lsum;
    __syncthreads();
    if (tid == 0) {
        const float s = wsum[0] + wsum[1] + wsum[2] + wsum[3];
        atomicAdd(&out[LOSS_OFF],     s * (1.0f  / (float)QELEMS));
        atomicAdd(&out[LOSS_OFF + 1], s * (0.25f / (float)QELEMS));
    }
}

extern "C" void kernel_launch(void* const* d_in, const int* in_sizes, int n_in,
                              void* d_out, int out_size, void* d_ws, size_t ws_size,
                              hipStream_t stream) {
    const float* in  = (const float*)d_in[0];   // (8, 64, 16, 32, 32) fp32
    const float* emb = (const float*)d_in[1];   // (1024, 64) fp32
    float* out = (float*)d_out;
    float* e2  = (float*)d_ws;                  // 1024 floats scratch

    vq_prep<<<4, 256, 0, stream>>>(emb, e2, out);
    vq_main<<<NTOT / BN, 256, 0, stream>>>(in, emb, e2, out);
}

// Round 3
// 166.133 us; speedup vs baseline: 1.9419x; 1.9419x over previous
//
#include <hip/hip_runtime.h>
#include <hip/hip_fp16.h>

// Problem: inputs (8, 64, 16, 32, 32) fp32, embedding (1024, 64) fp32
#define THW    16384
#define NTOT   131072
#define KDIM   1024
#define CDIM   64
#define QELEMS 8388608          // 8*64*16*32*32
#define LOSS_OFF 8388608
#define IDX_OFF  8388610
#define BN     128              // queries per block
#define KC     64               // codes staged per k-iter

typedef _Float16 half8  __attribute__((ext_vector_type(8)));
typedef _Float16 half4_t __attribute__((ext_vector_type(4)));
typedef float    f32x4  __attribute__((ext_vector_type(4)));

// ---- prep: zero losses; split E into fp16 hi/lo (lo scaled by 2^12); ||e||^2 ----
// grid 64 x 256 : block handles 16 code rows, 16 lanes per row (4 c's each)
__global__ __launch_bounds__(256) void vq_prep(const float* __restrict__ emb,
        _Float16* __restrict__ Eh, _Float16* __restrict__ El,
        float* __restrict__ e2, float* __restrict__ out) {
    const int t = threadIdx.x;
    if (blockIdx.x == 0 && t == 0) { out[LOSS_OFF] = 0.f; out[LOSS_OFF + 1] = 0.f; }
    const int row = blockIdx.x * 16 + (t >> 4);
    const int c0  = (t & 15) * 4;
    float4 v = *(const float4*)(emb + (size_t)row * CDIM + c0);
    const float xs[4] = {v.x, v.y, v.z, v.w};
    half4_t h, l;
    float s = 0.f;
    #pragma unroll
    for (int j = 0; j < 4; ++j) {
        const _Float16 hj = (_Float16)xs[j];
        const _Float16 lj = (_Float16)((xs[j] - (float)hj) * 4096.0f);
        h[j] = hj; l[j] = lj;
        s = fmaf(xs[j], xs[j], s);
    }
    *(half4_t*)(Eh + (size_t)row * CDIM + c0) = h;
    *(half4_t*)(El + (size_t)row * CDIM + c0) = l;
    #pragma unroll
    for (int off = 1; off < 16; off <<= 1) s += __shfl_xor(s, off, 64);
    if ((t & 15) == 0) e2[row] = s;
}

// ---- main: fp16x2 MFMA distances + argmin + gather/transpose + losses ----
__global__ __launch_bounds__(256, 3) void vq_main(const float* __restrict__ in,
        const float* __restrict__ emb,
        const _Float16* __restrict__ Eh, const _Float16* __restrict__ El,
        const float* __restrict__ e2, float* __restrict__ out) {

    // aliased LDS: [0,34816) = Xs(pre) / EhS+ElS(k-loop) / mv+mi(merge) / Q(epilogue)
    __shared__ char smem[36352];
    float    (*Xs)[68]  = (float (*)[68])smem;                 // [128][68] fp32
    _Float16 (*EhS)[72] = (_Float16 (*)[72])smem;              // [64][72]
    _Float16 (*ElS)[72] = (_Float16 (*)[72])(smem + 9216);
    float    (*Q)[68]   = (float (*)[68])smem;                 // [128][68]
    float* mv  = (float*)smem;                                 // [2][128]
    int*   mi  = (int*)(smem + 1024);                          // [2][128]
    float* x2p = (float*)(smem + 34816);                       // [2][128]
    int*   idxs = (int*)(smem + 34816 + 1024);                 // [128]

    const int tid  = threadIdx.x;
    const int n0   = blockIdx.x * BN;
    const int bb   = n0 >> 14;
    const int thw0 = n0 & (THW - 1);
    const float* inb = in  + (size_t)bb * CDIM * THW + thw0;
    float*      outb = out + (size_t)bb * CDIM * THW + thw0;

    // ---- stage X tile (fp32, transposed to [n][c]) + ||x||^2 partials ----
    {
        const int nl = tid & 127;
        const int hf = tid >> 7;
        float s = 0.f;
        #pragma unroll 8
        for (int r = 0; r < 32; ++r) {
            const int c = hf * 32 + r;
            const float x = inb[(size_t)c * THW + nl];
            Xs[nl][c] = x;
            s = fmaf(x, x, s);
        }
        x2p[hf * 128 + nl] = s;
    }
    __syncthreads();

    const int lane = tid & 63;
    const int w    = tid >> 6;
    const int ln   = lane & 15;
    const int lq   = lane >> 4;
    const int qb   = (w >> 1) * 64;     // query-half base for this wave
    const int cw   = (w & 1) * 2;       // code-tile base (2 of 4 tiles per chunk)

    // ---- build X fragments (fp16 hi/lo), held in registers for whole k-loop ----
    half8 Bh[4][2], Bl[4][2];
    #pragma unroll
    for (int qg = 0; qg < 4; ++qg) {
        const int q = qb + qg * 16 + ln;
        #pragma unroll
        for (int ch = 0; ch < 2; ++ch) {
            const float* xp = &Xs[q][ch * 32 + lq * 8];
            const float4 xa = *(const float4*)(xp);
            const float4 xb = *(const float4*)(xp + 4);
            const float xv[8] = {xa.x, xa.y, xa.z, xa.w, xb.x, xb.y, xb.z, xb.w};
            #pragma unroll
            for (int j = 0; j < 8; ++j) {
                const _Float16 h = (_Float16)xv[j];
                const _Float16 l = (_Float16)((xv[j] - (float)h) * 4096.0f);
                Bh[qg][ch][j] = h;
                Bl[qg][ch][j] = l;
            }
        }
    }
    __syncthreads();   // Xs dead; alias region becomes E staging

    float bestv[4];
    int   besti[4];
    #pragma unroll
    for (int qg = 0; qg < 4; ++qg) { bestv[qg] = 3.4e38f; besti[qg] = 0; }

    for (int k0 = 0; k0 < KDIM; k0 += KC) {
        // stage E chunk (hi+lo) into LDS, rows padded to 72 halves
        {
            const int row = tid >> 2;
            const int sg  = tid & 3;
            const float4* gh = (const float4*)(Eh + (size_t)(k0 + row) * CDIM + sg * 16);
            const float4* gl = (const float4*)(El + (size_t)(k0 + row) * CDIM + sg * 16);
            const float4 h0 = gh[0], h1 = gh[1];
            const float4 l0 = gl[0], l1 = gl[1];
            *(float4*)(&EhS[row][sg * 16])     = h0;
            *(float4*)(&EhS[row][sg * 16 + 8]) = h1;
            *(float4*)(&ElS[row][sg * 16])     = l0;
            *(float4*)(&ElS[row][sg * 16 + 8]) = l1;
        }
        __syncthreads();

        #pragma unroll
        for (int cc = 0; cc < 2; ++cc) {
            const int ctl = cw + cc;
            const half8 Ah0 = *(const half8*)(&EhS[ctl * 16 + ln][lq * 8]);
            const half8 Ah1 = *(const half8*)(&EhS[ctl * 16 + ln][32 + lq * 8]);
            const half8 Al0 = *(const half8*)(&ElS[ctl * 16 + ln][lq * 8]);
            const half8 Al1 = *(const half8*)(&ElS[ctl * 16 + ln][32 + lq * 8]);
            const float4 e2v = *(const float4*)(e2 + k0 + ctl * 16 + lq * 4);
            const float e2a[4] = {e2v.x, e2v.y, e2v.z, e2v.w};
            #pragma unroll
            for (int qg = 0; qg < 4; ++qg) {
                f32x4 a0 = {0.f, 0.f, 0.f, 0.f};
                f32x4 a1 = {0.f, 0.f, 0.f, 0.f};
                a0 = __builtin_amdgcn_mfma_f32_16x16x32_f16(Ah0, Bh[qg][0], a0, 0, 0, 0);
                a0 = __builtin_amdgcn_mfma_f32_16x16x32_f16(Ah1, Bh[qg][1], a0, 0, 0, 0);
                a1 = __builtin_amdgcn_mfma_f32_16x16x32_f16(Ah0, Bl[qg][0], a1, 0, 0, 0);
                a1 = __builtin_amdgcn_mfma_f32_16x16x32_f16(Al0, Bh[qg][0], a1, 0, 0, 0);
                a1 = __builtin_amdgcn_mfma_f32_16x16x32_f16(Ah1, Bl[qg][1], a1, 0, 0, 0);
                a1 = __builtin_amdgcn_mfma_f32_16x16x32_f16(Al1, Bh[qg][1], a1, 0, 0, 0);
                // d = ||e||^2 - 2*x.e ; x.e = a0 + 2^-12 * a1
                #pragma unroll
                for (int r = 0; r < 4; ++r) {
                    const float d = fmaf(-2.0f, a0[r], fmaf(-4.8828125e-4f, a1[r], e2a[r]));
                    const int kg = k0 + ctl * 16 + lq * 4 + r;
                    if (d < bestv[qg]) { bestv[qg] = d; besti[qg] = kg; }
                }
            }
        }
        __syncthreads();
    }

    // ---- wave-internal argmin reduce across the 4 row-quads (lexicographic) ----
    #pragma unroll
    for (int qg = 0; qg < 4; ++qg) {
        #pragma unroll
        for (int m = 16; m <= 32; m <<= 1) {
            const float ov = __shfl_xor(bestv[qg], m, 64);
            const int   oi = __shfl_xor(besti[qg], m, 64);
            if (ov < bestv[qg] || (ov == bestv[qg] && oi < besti[qg])) {
                bestv[qg] = ov; besti[qg] = oi;
            }
        }
    }
    if (lq == 0) {
        #pragma unroll
        for (int qg = 0; qg < 4; ++qg) {
            const int q = qb + qg * 16 + ln;
            mv[(w & 1) * 128 + q] = bestv[qg];
            mi[(w & 1) * 128 + q] = besti[qg];
        }
    }
    __syncthreads();

    // ---- merge code-halves; write indices; loss = sum(bestd + ||x||^2) ----
    float lsum = 0.f;
    if (tid < 128) {
        const int q = tid;
        float v0 = mv[q]; int i0 = mi[q];
        const float v1 = mv[128 + q]; const int i1 = mi[128 + q];
        if (v1 < v0 || (v1 == v0 && i1 < i0)) { v0 = v1; i0 = i1; }
        idxs[q] = i0;
        out[IDX_OFF + n0 + q] = (float)i0;
        lsum = v0 + x2p[q] + x2p[128 + q];
    }
    #pragma unroll
    for (int off = 32; off > 0; off >>= 1) lsum += __shfl_down(lsum, off, 64);
    if (lane == 0 && w < 2) {
        atomicAdd(&out[LOSS_OFF],     lsum * (1.0f  / (float)QELEMS));
        atomicAdd(&out[LOSS_OFF + 1], lsum * (0.25f / (float)QELEMS));
    }
    __syncthreads();

    // ---- epilogue: gather code rows coalesced into LDS, transpose-write ----
    {
        const int q  = tid >> 1;
        const int hf = tid & 1;
        const float* er = emb + (size_t)idxs[q] * CDIM + hf * 32;
        #pragma unroll
        for (int j = 0; j < 8; ++j) {
            const float4 v = *(const float4*)(er + 4 * j);
            *(float4*)(&Q[q][hf * 32 + 4 * j]) = v;
        }
    }
    __syncthreads();
    {
        const int nl = tid & 127;
        const int cb = tid >> 7;
        #pragma unroll 8
        for (int r = 0; r < 32; ++r) {
            const int c = 2 * r + cb;
            outb[(size_t)c * THW + nl] = Q[nl][c];
        }
    }
}

extern "C" void kernel_launch(void* const* d_in, const int* in_sizes, int n_in,
                              void* d_out, int out_size, void* d_ws, size_t ws_size,
                              hipStream_t stream) {
    const float* in  = (const float*)d_in[0];   // (8, 64, 16, 32, 32) fp32
    const float* emb = (const float*)d_in[1];   // (1024, 64) fp32
    float* out = (float*)d_out;
    _Float16* Eh = (_Float16*)d_ws;                         // 1024*64 halves
    _Float16* El = (_Float16*)((char*)d_ws + 131072);       // 1024*64 halves
    float*    e2 = (float*)((char*)d_ws + 262144);          // 1024 floats

    vq_prep<<<KDIM / 16, 256, 0, stream>>>(emb, Eh, El, e2, out);
    vq_main<<<NTOT / BN, 256, 0, stream>>>(in, emb, Eh, El, e2, out);
}